// Round 9
// baseline (114.900 us; speedup 1.0000x reference)
//
#include <hip/hip_runtime.h>
#include <hip/hip_bf16.h>

#define ALPHA 0.8f
#define SPB 64      // samples per block (encoder)
#define IVW 132     // tail LDS row stride

typedef __attribute__((ext_vector_type(8))) short bf16x8;
typedef __attribute__((ext_vector_type(8))) unsigned short ushort8;
typedef __attribute__((ext_vector_type(4))) float f32x4;

__device__ __forceinline__ unsigned short bfu(float x) {
    __hip_bfloat16 h = __float2bfloat16(x);   // RNE
    return __builtin_bit_cast(unsigned short, h);
}
__device__ __forceinline__ float b2f(unsigned short u) {
    return __builtin_bit_cast(float, ((unsigned)u) << 16);
}

// ---------------- prep kernels ----------------
// collapse r1+r2 into G[144][32], c[32]  (verified R0-R8)
__global__ void prepA(const float* __restrict__ Wr1, float* __restrict__ M) {
    int idx = blockIdx.x * 256 + threadIdx.x;
    if (idx >= 144 * 128) return;
    int x = idx >> 7;
    int r = idx & 127;
    const float* row = Wr1 + (size_t)r * 1024;
    float s = 0.f;
    if (x < 64) {
        #pragma unroll
        for (int j = 0; j < 8; ++j) s += row[j * 128 + x];
    } else if (x < 128) {
        #pragma unroll
        for (int j = 0; j < 8; ++j) s += row[j * 128 + 64 + (x - 64)];
    } else if (x < 136) {
        int j = x - 128;
        for (int k = 0; k < 64; ++k) s += row[j * 128 + k];
    } else {
        int j = x - 136;
        for (int k = 0; k < 64; ++k) s += row[j * 128 + 64 + k];
    }
    M[x * 128 + r] = s;
}

__global__ void prepB(const float* __restrict__ M, const float* __restrict__ Wr2,
                      const float* __restrict__ br1, const float* __restrict__ br2,
                      float* __restrict__ G, float* __restrict__ c) {
    int idx = blockIdx.x * 256 + threadIdx.x;
    if (idx < 144 * 32) {
        int x = idx >> 5, o = idx & 31;
        const float* m = M + x * 128;
        const float* w = Wr2 + o * 128;
        float s = 0.f;
        for (int r = 0; r < 128; ++r) s = fmaf(m[r], w[r], s);
        G[x * 32 + o] = s;
    } else if (idx < 144 * 32 + 32) {
        int o = idx - 144 * 32;
        const float* w = Wr2 + o * 128;
        float s = br2[o];
        for (int r = 0; r < 128; ++r) s = fmaf(br1[r], w[r], s);
        c[o] = s;
    }
}

// plain bf16 weight images: Wb1[64][768], Wb2[64][640] (zero-padded past 600)
__global__ void prepW(const float* __restrict__ We1, const float* __restrict__ We2,
                      unsigned short* __restrict__ Wb1, unsigned short* __restrict__ Wb2) {
    int i = blockIdx.x * 256 + threadIdx.x;
    if (i < 64 * 768) Wb1[i] = bfu(We1[i]);
    if (i < 64 * 640) {
        int r = i / 640, k = i - r * 640;
        Wb2[i] = (k < 600) ? bfu(We2[r * 600 + k]) : (unsigned short)0;
    }
}

// ---------------- encoder: barrier-free, LDS-free, per-wave streaming ----------------
// Wave w: 16 samples (rows w*16..w*16+15) x all 64 n. B-frags direct from L2-resident
// bf16 weight image; A-frags direct from global + in-register cvt. No __syncthreads
// anywhere -> no vmcnt(0) drains -> compiler keeps many loads in flight.
template <int NCH, int KPAD, int KLEN>
__device__ __forceinline__ void encNB(const float* __restrict__ X,
                                      const unsigned short* __restrict__ Wb,
                                      const float* __restrict__ bias,
                                      unsigned short* __restrict__ ivb,
                                      int colbase, int s0, int t) {
    const int w = t >> 6, l = t & 63;
    const int r16 = l & 15, kg = l >> 4;
    const float* xrow = X + (size_t)(s0 + w * 16 + r16) * KLEN;
    const unsigned short* wbA = Wb + (size_t)( 0 + r16) * KPAD;
    const unsigned short* wbB = Wb + (size_t)(16 + r16) * KPAD;
    const unsigned short* wbC = Wb + (size_t)(32 + r16) * KPAD;
    const unsigned short* wbD = Wb + (size_t)(48 + r16) * KPAD;

    f32x4 acc0 = {0.f,0.f,0.f,0.f}, acc1 = {0.f,0.f,0.f,0.f};
    f32x4 acc2 = {0.f,0.f,0.f,0.f}, acc3 = {0.f,0.f,0.f,0.f};

    #pragma unroll 4
    for (int kk = 0; kk < NCH; ++kk) {
        const int kb = kk * 32 + kg * 8;
        ushort8 pa;
        #pragma unroll
        for (int e = 0; e < 8; ++e) pa[e] = 0;
        if (KPAD == KLEN || kb + 8 <= KLEN) {
            const f32x4 u = *(const f32x4*)(xrow + kb);
            const f32x4 v = *(const f32x4*)(xrow + kb + 4);
            pa[0] = bfu(u[0]); pa[1] = bfu(u[1]); pa[2] = bfu(u[2]); pa[3] = bfu(u[3]);
            pa[4] = bfu(v[0]); pa[5] = bfu(v[1]); pa[6] = bfu(v[2]); pa[7] = bfu(v[3]);
        }
        const bf16x8 af = __builtin_bit_cast(bf16x8, pa);
        const bf16x8 b0 = *(const bf16x8*)(wbA + kb);
        const bf16x8 b1 = *(const bf16x8*)(wbB + kb);
        const bf16x8 b2 = *(const bf16x8*)(wbC + kb);
        const bf16x8 b3 = *(const bf16x8*)(wbD + kb);
        acc0 = __builtin_amdgcn_mfma_f32_16x16x32_bf16(af, b0, acc0, 0, 0, 0);
        acc1 = __builtin_amdgcn_mfma_f32_16x16x32_bf16(af, b1, acc1, 0, 0, 0);
        acc2 = __builtin_amdgcn_mfma_f32_16x16x32_bf16(af, b2, acc2, 0, 0, 0);
        acc3 = __builtin_amdgcn_mfma_f32_16x16x32_bf16(af, b3, acc3, 0, 0, 0);
    }

    // C/D: col = lane&15 (=n offset), row = 4*(lane>>4)+reg (=sample offset)
    const float bz0 = bias[r16], bz1 = bias[16 + r16], bz2 = bias[32 + r16], bz3 = bias[48 + r16];
    const int rr = 4 * kg;
    #pragma unroll
    for (int reg = 0; reg < 4; ++reg) {
        const size_t base = (size_t)(s0 + w * 16 + rr + reg) * 128 + colbase;
        ivb[base +  0 + r16] = bfu(acc0[reg] + bz0);
        ivb[base + 16 + r16] = bfu(acc1[reg] + bz1);
        ivb[base + 32 + r16] = bfu(acc2[reg] + bz2);
        ivb[base + 48 + r16] = bfu(acc3[reg] + bz3);
    }
}

__global__ __launch_bounds__(256, 2)
void mica_enc(const float* __restrict__ f1, const float* __restrict__ f2,
              const unsigned short* __restrict__ Wb1, const unsigned short* __restrict__ Wb2,
              const float* __restrict__ be1, const float* __restrict__ be2,
              unsigned short* __restrict__ ivb) {
    const int t = threadIdx.x;
    const int s0 = blockIdx.x * SPB;
    encNB<24, 768, 768>(f1, Wb1, be1, ivb, 0,  s0, t);
    encNB<20, 640, 600>(f2, Wb2, be2, ivb, 64, s0, t);
}

// ---------------- tail (R8, verified; LDS form, no spills) ----------------
__global__ __launch_bounds__(256, 2)
void mica_tail(const unsigned short* __restrict__ ivb,
               const float* __restrict__ Waffa, const float* __restrict__ Waffv,
               const float* __restrict__ Wa, const float* __restrict__ Wv,
               const float* __restrict__ Wca, const float* __restrict__ Wcv,
               const float* __restrict__ Wha, const float* __restrict__ Whv,
               const float* __restrict__ G, const float* __restrict__ cvec,
               float* __restrict__ out) {
    __shared__ float sIV[SPB * IVW];    // 33.8 KB
    __shared__ float red[4096];         // 16 KB reduction buffer
    const int t = threadIdx.x;
    const int s0 = blockIdx.x * SPB;

    // stage: thread handles row = t&63, 32 cols at cb = (t>>6)*32
    {
        const int row = t & 63, cb = (t >> 6) * 32;
        const unsigned short* src = ivb + (size_t)(s0 + row) * 128 + cb;
        #pragma unroll
        for (int j = 0; j < 4; ++j) {
            const ushort8 v = *(const ushort8*)(src + j * 8);
            f32x4 f0 = {b2f(v[0]), b2f(v[1]), b2f(v[2]), b2f(v[3])};
            f32x4 f1 = {b2f(v[4]), b2f(v[5]), b2f(v[6]), b2f(v[7])};
            *(f32x4*)(sIV + row * IVW + cb + j * 8)     = f0;
            *(f32x4*)(sIV + row * IVW + cb + j * 8 + 4) = f1;
        }
    }
    __syncthreads();

    const int s = t & 63;
    const int q = t >> 6;
    const float* iv = sIV + s * IVW;

    // step 3: moments (4-way split over k, 16 k each)
    float sii = 0.f, siv = 0.f, svv = 0.f;
    #pragma unroll
    for (int h = 0; h < 2; ++h) {
        const f32x4 a0 = *(const f32x4*)(iv + q * 16 + h * 8);
        const f32x4 a1 = *(const f32x4*)(iv + q * 16 + h * 8 + 4);
        const f32x4 b0 = *(const f32x4*)(iv + 64 + q * 16 + h * 8);
        const f32x4 b1 = *(const f32x4*)(iv + 64 + q * 16 + h * 8 + 4);
        #pragma unroll
        for (int j = 0; j < 4; ++j) {
            sii = fmaf(a0[j], a0[j], sii); siv = fmaf(a0[j], b0[j], siv); svv = fmaf(b0[j], b0[j], svv);
            sii = fmaf(a1[j], a1[j], sii); siv = fmaf(a1[j], b1[j], siv); svv = fmaf(b1[j], b1[j], svv);
        }
    }
    red[(q * 3 + 0) * 64 + s] = sii;
    red[(q * 3 + 1) * 64 + s] = siv;
    red[(q * 3 + 2) * 64 + s] = svv;
    __syncthreads();
    sii = 0.f; siv = 0.f; svv = 0.f;
    #pragma unroll
    for (int g = 0; g < 4; ++g) {
        sii += red[(g * 3 + 0) * 64 + s];
        siv += red[(g * 3 + 1) * 64 + s];
        svv += red[(g * 3 + 2) * 64 + s];
    }

    // step 4: gates (scale = 1/8)
    float ia[8], va[8];
    #pragma unroll
    for (int j = 0; j < 8; ++j) {
        ia[j] = tanhf((sii * Waffa[j * 2 + 0] + siv * Waffa[j * 2 + 1]) * 0.125f);
        va[j] = tanhf((siv * Waffv[j * 2 + 0] + svv * Waffv[j * 2 + 1]) * 0.125f);
    }

    // steps 5-6: H_a, H_v — this thread owns m = q*8 .. q*8+7
    float Ha[8], Hv[8];
    #pragma unroll
    for (int mi = 0; mi < 8; ++mi) {
        const int m = q * 8 + mi;
        float sa = 0.f, sv = 0.f;
        #pragma unroll
        for (int j = 0; j < 8; ++j) {
            sa = fmaf(ia[j], Wca[m * 8 + j], sa);
            sv = fmaf(va[j], Wcv[m * 8 + j], sv);
        }
        Ha[mi] = sa; Hv[mi] = sv;
    }
    for (int k4 = 0; k4 < 64; k4 += 4) {
        const f32x4 a4 = *(const f32x4*)(iv + k4);
        const f32x4 b4 = *(const f32x4*)(iv + 64 + k4);
        #pragma unroll
        for (int mi = 0; mi < 8; ++mi) {
            const int m = q * 8 + mi;
            const f32x4 wa = *(const f32x4*)(Wa + m * 64 + k4);
            const f32x4 wv = *(const f32x4*)(Wv + m * 64 + k4);
            #pragma unroll
            for (int j = 0; j < 4; ++j) {
                Ha[mi] = fmaf(a4[j], wa[j], Ha[mi]);
                Hv[mi] = fmaf(b4[j], wv[j], Hv[mi]);
            }
        }
    }
    #pragma unroll
    for (int mi = 0; mi < 8; ++mi) {
        Ha[mi] = fmaxf(ALPHA * Ha[mi], 0.f);
        Hv[mi] = fmaxf((1.f - ALPHA) * Hv[mi], 0.f);
    }

    __syncthreads();   // step-3 reads of red done before step-7 writes

    // step 7: ha/hv partials (8 m each), reduce via red
    #pragma unroll
    for (int j = 0; j < 8; ++j) {
        float hap = 0.f, hvp = 0.f;
        #pragma unroll
        for (int mi = 0; mi < 8; ++mi) {
            hap = fmaf(Ha[mi], Wha[j * 32 + q * 8 + mi], hap);
            hvp = fmaf(Hv[mi], Whv[j * 32 + q * 8 + mi], hvp);
        }
        red[(q * 16 + j) * 64 + s] = hap;
        red[(q * 16 + 8 + j) * 64 + s] = hvp;
    }
    __syncthreads();
    float ha[8], hv[8];
    #pragma unroll
    for (int j = 0; j < 8; ++j) {
        float sa = 0.f, sv = 0.f;
        #pragma unroll
        for (int g = 0; g < 4; ++g) {
            sa += red[(g * 16 + j) * 64 + s];
            sv += red[(g * 16 + 8 + j) * 64 + s];
        }
        ha[j] = sa; hv[j] = sv;
    }

    // step 9: out = X[144] * G + c — this thread: o = q*8 .. q*8+7
    float o8[8];
    #pragma unroll
    for (int oi = 0; oi < 8; ++oi) o8[oi] = cvec[q * 8 + oi];
    for (int k4 = 0; k4 < 128; k4 += 4) {
        const f32x4 a4 = *(const f32x4*)(iv + k4);
        #pragma unroll
        for (int kk = 0; kk < 4; ++kk) {
            const f32x4 g0 = *(const f32x4*)(G + (k4 + kk) * 32 + q * 8);
            const f32x4 g1 = *(const f32x4*)(G + (k4 + kk) * 32 + q * 8 + 4);
            #pragma unroll
            for (int oi = 0; oi < 4; ++oi) {
                o8[oi]     = fmaf(a4[kk], g0[oi], o8[oi]);
                o8[4 + oi] = fmaf(a4[kk], g1[oi], o8[4 + oi]);
            }
        }
    }
    #pragma unroll
    for (int j = 0; j < 8; ++j) {
        const float aj = ALPHA * ha[j];
        const float vj = (1.f - ALPHA) * hv[j];
        const f32x4 ga0 = *(const f32x4*)(G + (128 + j) * 32 + q * 8);
        const f32x4 ga1 = *(const f32x4*)(G + (128 + j) * 32 + q * 8 + 4);
        const f32x4 gv0 = *(const f32x4*)(G + (136 + j) * 32 + q * 8);
        const f32x4 gv1 = *(const f32x4*)(G + (136 + j) * 32 + q * 8 + 4);
        #pragma unroll
        for (int oi = 0; oi < 4; ++oi) {
            o8[oi]     = fmaf(aj, ga0[oi], o8[oi]);
            o8[4 + oi] = fmaf(aj, ga1[oi], o8[4 + oi]);
            o8[oi]     = fmaf(vj, gv0[oi], o8[oi]);
            o8[4 + oi] = fmaf(vj, gv1[oi], o8[4 + oi]);
        }
    }
    f32x4 v0 = {o8[0], o8[1], o8[2], o8[3]};
    f32x4 v1 = {o8[4], o8[5], o8[6], o8[7]};
    float* op = out + (size_t)(s0 + s) * 32 + q * 8;
    *(f32x4*)op = v0;
    *((f32x4*)op + 1) = v1;
}

extern "C" void kernel_launch(void* const* d_in, const int* in_sizes, int n_in,
                              void* d_out, int out_size, void* d_ws, size_t ws_size,
                              hipStream_t stream) {
    const float* f1    = (const float*)d_in[0];
    const float* f2    = (const float*)d_in[1];
    const float* We1   = (const float*)d_in[2];
    const float* be1   = (const float*)d_in[3];
    const float* We2   = (const float*)d_in[4];
    const float* be2   = (const float*)d_in[5];
    const float* Waffa = (const float*)d_in[6];
    const float* Waffv = (const float*)d_in[7];
    const float* Wa    = (const float*)d_in[8];
    const float* Wv    = (const float*)d_in[9];
    const float* Wca   = (const float*)d_in[10];
    const float* Wcv   = (const float*)d_in[11];
    const float* Wha   = (const float*)d_in[12];
    const float* Whv   = (const float*)d_in[13];
    const float* Wr1   = (const float*)d_in[14];
    const float* br1   = (const float*)d_in[15];
    const float* Wr2   = (const float*)d_in[16];
    const float* br2   = (const float*)d_in[17];
    float* outp = (float*)d_out;

    const int Btot = in_sizes[0] / 768;

    // ws layout: M[0,73728) G[73728,92160) c[92160,92288)
    //            Wb1[92288,+98304) Wb2[190592,+81920) ivb[272512, +B*256)
    float* M = (float*)d_ws;
    float* G = (float*)((char*)d_ws + 73728);
    float* c = (float*)((char*)d_ws + 92160);
    unsigned short* Wb1 = (unsigned short*)((char*)d_ws + 92288);
    unsigned short* Wb2 = (unsigned short*)((char*)d_ws + 190592);
    unsigned short* ivb = (unsigned short*)((char*)d_ws + 272512);

    prepA<<<(144 * 128 + 255) / 256, 256, 0, stream>>>(Wr1, M);
    prepB<<<(144 * 32 + 32 + 255) / 256, 256, 0, stream>>>(M, Wr2, br1, br2, G, c);
    prepW<<<(64 * 768 + 255) / 256, 256, 0, stream>>>(We1, We2, Wb1, Wb2);
    mica_enc<<<Btot / SPB, 256, 0, stream>>>(f1, f2, Wb1, Wb2, be1, be2, ivb);
    mica_tail<<<Btot / SPB, 256, 0, stream>>>(ivb, Waffa, Waffv, Wa, Wv,
                                              Wca, Wcv, Wha, Whv, G, c, outp);
}

// Round 10
// 88.264 us; speedup vs baseline: 1.3018x; 1.3018x over previous
//
#include <hip/hip_runtime.h>
#include <hip/hip_bf16.h>

#define ALPHA 0.8f
#define SPB 64      // samples per block (encoder)
#define IVW 132     // tail LDS row stride

typedef __attribute__((ext_vector_type(8))) short bf16x8;
typedef __attribute__((ext_vector_type(8))) unsigned short ushort8;
typedef __attribute__((ext_vector_type(4))) unsigned short ushort4v;
typedef __attribute__((ext_vector_type(4))) float f32x4;

__device__ __forceinline__ unsigned short bfu(float x) {
    __hip_bfloat16 h = __float2bfloat16(x);   // RNE
    return __builtin_bit_cast(unsigned short, h);
}
__device__ __forceinline__ float b2f(unsigned short u) {
    return __builtin_bit_cast(float, ((unsigned)u) << 16);
}

// ---------------- prep kernels ----------------
// collapse r1+r2 into G[144][32], c[32]  (verified R0-R9)
__global__ void prepA(const float* __restrict__ Wr1, float* __restrict__ M) {
    int idx = blockIdx.x * 256 + threadIdx.x;
    if (idx >= 144 * 128) return;
    int x = idx >> 7;
    int r = idx & 127;
    const float* row = Wr1 + (size_t)r * 1024;
    float s = 0.f;
    if (x < 64) {
        #pragma unroll
        for (int j = 0; j < 8; ++j) s += row[j * 128 + x];
    } else if (x < 128) {
        #pragma unroll
        for (int j = 0; j < 8; ++j) s += row[j * 128 + 64 + (x - 64)];
    } else if (x < 136) {
        int j = x - 128;
        for (int k = 0; k < 64; ++k) s += row[j * 128 + k];
    } else {
        int j = x - 136;
        for (int k = 0; k < 64; ++k) s += row[j * 128 + 64 + k];
    }
    M[x * 128 + r] = s;
}

__global__ void prepB(const float* __restrict__ M, const float* __restrict__ Wr2,
                      const float* __restrict__ br1, const float* __restrict__ br2,
                      float* __restrict__ G, float* __restrict__ c) {
    int idx = blockIdx.x * 256 + threadIdx.x;
    if (idx < 144 * 32) {
        int x = idx >> 5, o = idx & 31;
        const float* m = M + x * 128;
        const float* w = Wr2 + o * 128;
        float s = 0.f;
        for (int r = 0; r < 128; ++r) s = fmaf(m[r], w[r], s);
        G[x * 32 + o] = s;
    } else if (idx < 144 * 32 + 32) {
        int o = idx - 144 * 32;
        const float* w = Wr2 + o * 128;
        float s = br2[o];
        for (int r = 0; r < 128; ++r) s = fmaf(br1[r], w[r], s);
        c[o] = s;
    }
}

// Pack weights into MFMA B-fragment order: Wf[frag_id][lane][8 bf16], 1 KB per frag.
// frag_id = (kblk*4 + kk)*4 + nt ;  element: W[nt*16 + (lane&15)][ks*32 + (lane>>4)*8 + e]
// enc1: 6 kblk * 4 kk * 4 nt = 96 frags (96 KB); enc2: 5*4*4 = 80 frags (80 KB, zero k>=600)
__global__ void prepWf(const float* __restrict__ We1, const float* __restrict__ We2,
                       unsigned short* __restrict__ Wf1, unsigned short* __restrict__ Wf2) {
    int idx = blockIdx.x * 256 + threadIdx.x;
    if (idx >= 11264) return;
    const bool e2 = idx >= 6144;
    const int f = e2 ? idx - 6144 : idx;
    const int lane = f & 63, frag = f >> 6;
    const int nt = frag & 3, ks = frag >> 2;
    const int row = nt * 16 + (lane & 15);
    const int k0 = ks * 32 + (lane >> 4) * 8;
    ushort8 v;
    if (!e2) {
        const float* wr = We1 + (size_t)row * 768 + k0;
        #pragma unroll
        for (int e = 0; e < 8; ++e) v[e] = bfu(wr[e]);
        *(ushort8*)(Wf1 + (size_t)frag * 512 + lane * 8) = v;
    } else {
        #pragma unroll
        for (int e = 0; e < 8; ++e) {
            const int k = k0 + e;
            v[e] = (k < 600) ? bfu(We2[(size_t)row * 600 + k]) : (unsigned short)0;
        }
        *(ushort8*)(Wf2 + (size_t)frag * 512 + lane * 8) = v;
    }
}

// ---------------- encoder: wave-synchronous, zero __syncthreads ----------------
// Wave owns 16 samples x all 64 n. Per 128-k window:
//  - A staged via 8 coalesced loads (2x512B rows/instr) -> cvt -> swizzled ds_write
//  - B frags: 16 fully-coalesced 1KB loads from the packed Wf image (L1/L2 resident)
//  - 4 ds_read_b128 A-frags (XOR swizzle, <=2-way banks) + 16 MFMA
// Next window's A loads are issued before the MFMA block (fly under compute).
template <int KLEN, int NWIN>
__device__ __forceinline__ void encW(const float* __restrict__ X,
                                     const unsigned short* __restrict__ Wf,
                                     const float* __restrict__ bias,
                                     unsigned short* __restrict__ lds,   // wave-private, 2 x 2048 ushorts
                                     unsigned short* __restrict__ ivb,
                                     int colbase, int s0w, int l) {
    const int r16 = l & 15, kg = l >> 4;
    const int srow = l >> 5;          // row parity within staging pair
    const int q = l & 31;             // float-quad within 128-k window
    const int ch = q >> 1, hh = q & 1;

    f32x4 acc0 = {0.f,0.f,0.f,0.f}, acc1 = {0.f,0.f,0.f,0.f};
    f32x4 acc2 = {0.f,0.f,0.f,0.f}, acc3 = {0.f,0.f,0.f,0.f};
    f32x4 rv[8];

    // prologue: stage window 0 (always fully in-bounds: 4q+4 <= 128 <= KLEN)
    #pragma unroll
    for (int j = 0; j < 8; ++j) {
        const int row = 2 * j + srow;
        rv[j] = *(const f32x4*)(X + (size_t)(s0w + row) * KLEN + 4 * q);
    }

    #pragma unroll
    for (int wnd = 0; wnd < NWIN; ++wnd) {
        unsigned short* buf = lds + (wnd & 1) * 2048;
        // cvt + swizzled ds_write of current window
        #pragma unroll
        for (int j = 0; j < 8; ++j) {
            const int row = 2 * j + srow;
            ushort4v pk;
            pk[0] = bfu(rv[j][0]); pk[1] = bfu(rv[j][1]);
            pk[2] = bfu(rv[j][2]); pk[3] = bfu(rv[j][3]);
            *(ushort4v*)((char*)buf + row * 256 +
                         ((ch & 8) | ((ch & 7) ^ (row & 7))) * 16 + hh * 8) = pk;
        }
        // issue next-window A loads (in flight across B-loads + MFMAs)
        if (wnd + 1 < NWIN) {
            const int kb1 = (wnd + 1) * 128;
            #pragma unroll
            for (int j = 0; j < 8; ++j) {
                const int row = 2 * j + srow;
                if (KLEN % 128 == 0 || kb1 + 4 * q + 4 <= KLEN) {
                    rv[j] = *(const f32x4*)(X + (size_t)(s0w + row) * KLEN + kb1 + 4 * q);
                } else {
                    f32x4 z = {0.f,0.f,0.f,0.f};
                    rv[j] = z;
                }
            }
        }
        // B frags: 16 coalesced 1 KB loads
        const unsigned short* wfw = Wf + (size_t)wnd * 16 * 512 + l * 8;
        bf16x8 bb[16];
        #pragma unroll
        for (int i = 0; i < 16; ++i) bb[i] = *(const bf16x8*)(wfw + i * 512);
        // A frags + MFMA
        #pragma unroll
        for (int kk = 0; kk < 4; ++kk) {
            const int cc = kk * 4 + kg;
            const bf16x8 af = *(const bf16x8*)((const char*)buf + r16 * 256 +
                                 ((cc & 8) | ((cc & 7) ^ (r16 & 7))) * 16);
            acc0 = __builtin_amdgcn_mfma_f32_16x16x32_bf16(af, bb[kk * 4 + 0], acc0, 0, 0, 0);
            acc1 = __builtin_amdgcn_mfma_f32_16x16x32_bf16(af, bb[kk * 4 + 1], acc1, 0, 0, 0);
            acc2 = __builtin_amdgcn_mfma_f32_16x16x32_bf16(af, bb[kk * 4 + 2], acc2, 0, 0, 0);
            acc3 = __builtin_amdgcn_mfma_f32_16x16x32_bf16(af, bb[kk * 4 + 3], acc3, 0, 0, 0);
        }
    }

    // epilogue: bias + ivb store (C/D: col=lane&15, row=4*(lane>>4)+reg)
    const float bz0 = bias[r16], bz1 = bias[16 + r16], bz2 = bias[32 + r16], bz3 = bias[48 + r16];
    const int rr = 4 * kg;
    #pragma unroll
    for (int reg = 0; reg < 4; ++reg) {
        const size_t base = (size_t)(s0w + rr + reg) * 128 + colbase;
        ivb[base +  0 + r16] = bfu(acc0[reg] + bz0);
        ivb[base + 16 + r16] = bfu(acc1[reg] + bz1);
        ivb[base + 32 + r16] = bfu(acc2[reg] + bz2);
        ivb[base + 48 + r16] = bfu(acc3[reg] + bz3);
    }
}

__global__ __launch_bounds__(256)
void mica_enc(const float* __restrict__ f1, const float* __restrict__ f2,
              const unsigned short* __restrict__ Wf1, const unsigned short* __restrict__ Wf2,
              const float* __restrict__ be1, const float* __restrict__ be2,
              unsigned short* __restrict__ ivb) {
    __shared__ __align__(16) unsigned short lds[4 * 2 * 2048];   // 32 KB, wave-private slices
    const int t = threadIdx.x;
    const int w = t >> 6, l = t & 63;
    unsigned short* ldsw = lds + w * 4096;
    const int s0w = blockIdx.x * SPB + w * 16;
    encW<768, 6>(f1, Wf1, be1, ldsw, ivb, 0,  s0w, l);
    encW<600, 5>(f2, Wf2, be2, ldsw, ivb, 64, s0w, l);
}

// ---------------- tail (R8/R9, verified; LDS form, no spills) ----------------
__global__ __launch_bounds__(256, 2)
void mica_tail(const unsigned short* __restrict__ ivb,
               const float* __restrict__ Waffa, const float* __restrict__ Waffv,
               const float* __restrict__ Wa, const float* __restrict__ Wv,
               const float* __restrict__ Wca, const float* __restrict__ Wcv,
               const float* __restrict__ Wha, const float* __restrict__ Whv,
               const float* __restrict__ G, const float* __restrict__ cvec,
               float* __restrict__ out) {
    __shared__ float sIV[SPB * IVW];    // 33.8 KB
    __shared__ float red[4096];         // 16 KB reduction buffer
    const int t = threadIdx.x;
    const int s0 = blockIdx.x * SPB;

    // stage: thread handles row = t&63, 32 cols at cb = (t>>6)*32
    {
        const int row = t & 63, cb = (t >> 6) * 32;
        const unsigned short* src = ivb + (size_t)(s0 + row) * 128 + cb;
        #pragma unroll
        for (int j = 0; j < 4; ++j) {
            const ushort8 v = *(const ushort8*)(src + j * 8);
            f32x4 f0 = {b2f(v[0]), b2f(v[1]), b2f(v[2]), b2f(v[3])};
            f32x4 f1 = {b2f(v[4]), b2f(v[5]), b2f(v[6]), b2f(v[7])};
            *(f32x4*)(sIV + row * IVW + cb + j * 8)     = f0;
            *(f32x4*)(sIV + row * IVW + cb + j * 8 + 4) = f1;
        }
    }
    __syncthreads();

    const int s = t & 63;
    const int q = t >> 6;
    const float* iv = sIV + s * IVW;

    // step 3: moments (4-way split over k, 16 k each)
    float sii = 0.f, siv = 0.f, svv = 0.f;
    #pragma unroll
    for (int h = 0; h < 2; ++h) {
        const f32x4 a0 = *(const f32x4*)(iv + q * 16 + h * 8);
        const f32x4 a1 = *(const f32x4*)(iv + q * 16 + h * 8 + 4);
        const f32x4 b0 = *(const f32x4*)(iv + 64 + q * 16 + h * 8);
        const f32x4 b1 = *(const f32x4*)(iv + 64 + q * 16 + h * 8 + 4);
        #pragma unroll
        for (int j = 0; j < 4; ++j) {
            sii = fmaf(a0[j], a0[j], sii); siv = fmaf(a0[j], b0[j], siv); svv = fmaf(b0[j], b0[j], svv);
            sii = fmaf(a1[j], a1[j], sii); siv = fmaf(a1[j], b1[j], siv); svv = fmaf(b1[j], b1[j], svv);
        }
    }
    red[(q * 3 + 0) * 64 + s] = sii;
    red[(q * 3 + 1) * 64 + s] = siv;
    red[(q * 3 + 2) * 64 + s] = svv;
    __syncthreads();
    sii = 0.f; siv = 0.f; svv = 0.f;
    #pragma unroll
    for (int g = 0; g < 4; ++g) {
        sii += red[(g * 3 + 0) * 64 + s];
        siv += red[(g * 3 + 1) * 64 + s];
        svv += red[(g * 3 + 2) * 64 + s];
    }

    // step 4: gates (scale = 1/8)
    float ia[8], va[8];
    #pragma unroll
    for (int j = 0; j < 8; ++j) {
        ia[j] = tanhf((sii * Waffa[j * 2 + 0] + siv * Waffa[j * 2 + 1]) * 0.125f);
        va[j] = tanhf((siv * Waffv[j * 2 + 0] + svv * Waffv[j * 2 + 1]) * 0.125f);
    }

    // steps 5-6: H_a, H_v — this thread owns m = q*8 .. q*8+7
    float Ha[8], Hv[8];
    #pragma unroll
    for (int mi = 0; mi < 8; ++mi) {
        const int m = q * 8 + mi;
        float sa = 0.f, sv = 0.f;
        #pragma unroll
        for (int j = 0; j < 8; ++j) {
            sa = fmaf(ia[j], Wca[m * 8 + j], sa);
            sv = fmaf(va[j], Wcv[m * 8 + j], sv);
        }
        Ha[mi] = sa; Hv[mi] = sv;
    }
    for (int k4 = 0; k4 < 64; k4 += 4) {
        const f32x4 a4 = *(const f32x4*)(iv + k4);
        const f32x4 b4 = *(const f32x4*)(iv + 64 + k4);
        #pragma unroll
        for (int mi = 0; mi < 8; ++mi) {
            const int m = q * 8 + mi;
            const f32x4 wa = *(const f32x4*)(Wa + m * 64 + k4);
            const f32x4 wv = *(const f32x4*)(Wv + m * 64 + k4);
            #pragma unroll
            for (int j = 0; j < 4; ++j) {
                Ha[mi] = fmaf(a4[j], wa[j], Ha[mi]);
                Hv[mi] = fmaf(b4[j], wv[j], Hv[mi]);
            }
        }
    }
    #pragma unroll
    for (int mi = 0; mi < 8; ++mi) {
        Ha[mi] = fmaxf(ALPHA * Ha[mi], 0.f);
        Hv[mi] = fmaxf((1.f - ALPHA) * Hv[mi], 0.f);
    }

    __syncthreads();   // step-3 reads of red done before step-7 writes

    // step 7: ha/hv partials (8 m each), reduce via red
    #pragma unroll
    for (int j = 0; j < 8; ++j) {
        float hap = 0.f, hvp = 0.f;
        #pragma unroll
        for (int mi = 0; mi < 8; ++mi) {
            hap = fmaf(Ha[mi], Wha[j * 32 + q * 8 + mi], hap);
            hvp = fmaf(Hv[mi], Whv[j * 32 + q * 8 + mi], hvp);
        }
        red[(q * 16 + j) * 64 + s] = hap;
        red[(q * 16 + 8 + j) * 64 + s] = hvp;
    }
    __syncthreads();
    float ha[8], hv[8];
    #pragma unroll
    for (int j = 0; j < 8; ++j) {
        float sa = 0.f, sv = 0.f;
        #pragma unroll
        for (int g = 0; g < 4; ++g) {
            sa += red[(g * 16 + j) * 64 + s];
            sv += red[(g * 16 + 8 + j) * 64 + s];
        }
        ha[j] = sa; hv[j] = sv;
    }

    // step 9: out = X[144] * G + c — this thread: o = q*8 .. q*8+7
    float o8[8];
    #pragma unroll
    for (int oi = 0; oi < 8; ++oi) o8[oi] = cvec[q * 8 + oi];
    for (int k4 = 0; k4 < 128; k4 += 4) {
        const f32x4 a4 = *(const f32x4*)(iv + k4);
        #pragma unroll
        for (int kk = 0; kk < 4; ++kk) {
            const f32x4 g0 = *(const f32x4*)(G + (k4 + kk) * 32 + q * 8);
            const f32x4 g1 = *(const f32x4*)(G + (k4 + kk) * 32 + q * 8 + 4);
            #pragma unroll
            for (int oi = 0; oi < 4; ++oi) {
                o8[oi]     = fmaf(a4[kk], g0[oi], o8[oi]);
                o8[4 + oi] = fmaf(a4[kk], g1[oi], o8[4 + oi]);
            }
        }
    }
    #pragma unroll
    for (int j = 0; j < 8; ++j) {
        const float aj = ALPHA * ha[j];
        const float vj = (1.f - ALPHA) * hv[j];
        const f32x4 ga0 = *(const f32x4*)(G + (128 + j) * 32 + q * 8);
        const f32x4 ga1 = *(const f32x4*)(G + (128 + j) * 32 + q * 8 + 4);
        const f32x4 gv0 = *(const f32x4*)(G + (136 + j) * 32 + q * 8);
        const f32x4 gv1 = *(const f32x4*)(G + (136 + j) * 32 + q * 8 + 4);
        #pragma unroll
        for (int oi = 0; oi < 4; ++oi) {
            o8[oi]     = fmaf(aj, ga0[oi], o8[oi]);
            o8[4 + oi] = fmaf(aj, ga1[oi], o8[4 + oi]);
            o8[oi]     = fmaf(vj, gv0[oi], o8[oi]);
            o8[4 + oi] = fmaf(vj, gv1[oi], o8[4 + oi]);
        }
    }
    f32x4 v0 = {o8[0], o8[1], o8[2], o8[3]};
    f32x4 v1 = {o8[4], o8[5], o8[6], o8[7]};
    float* op = out + (size_t)(s0 + s) * 32 + q * 8;
    *(f32x4*)op = v0;
    *((f32x4*)op + 1) = v1;
}

extern "C" void kernel_launch(void* const* d_in, const int* in_sizes, int n_in,
                              void* d_out, int out_size, void* d_ws, size_t ws_size,
                              hipStream_t stream) {
    const float* f1    = (const float*)d_in[0];
    const float* f2    = (const float*)d_in[1];
    const float* We1   = (const float*)d_in[2];
    const float* be1   = (const float*)d_in[3];
    const float* We2   = (const float*)d_in[4];
    const float* be2   = (const float*)d_in[5];
    const float* Waffa = (const float*)d_in[6];
    const float* Waffv = (const float*)d_in[7];
    const float* Wa    = (const float*)d_in[8];
    const float* Wv    = (const float*)d_in[9];
    const float* Wca   = (const float*)d_in[10];
    const float* Wcv   = (const float*)d_in[11];
    const float* Wha   = (const float*)d_in[12];
    const float* Whv   = (const float*)d_in[13];
    const float* Wr1   = (const float*)d_in[14];
    const float* br1   = (const float*)d_in[15];
    const float* Wr2   = (const float*)d_in[16];
    const float* br2   = (const float*)d_in[17];
    float* outp = (float*)d_out;

    const int Btot = in_sizes[0] / 768;

    // ws layout: M[0,73728) G[73728,92160) c[92160,92288)
    //            Wf1[92288,+98304) Wf2[190592,+81920) ivb[272512, +B*256)
    float* M = (float*)d_ws;
    float* G = (float*)((char*)d_ws + 73728);
    float* c = (float*)((char*)d_ws + 92160);
    unsigned short* Wf1 = (unsigned short*)((char*)d_ws + 92288);
    unsigned short* Wf2 = (unsigned short*)((char*)d_ws + 190592);
    unsigned short* ivb = (unsigned short*)((char*)d_ws + 272512);

    prepA<<<(144 * 128 + 255) / 256, 256, 0, stream>>>(Wr1, M);
    prepB<<<(144 * 32 + 32 + 255) / 256, 256, 0, stream>>>(M, Wr2, br1, br2, G, c);
    prepWf<<<44, 256, 0, stream>>>(We1, We2, Wf1, Wf2);
    mica_enc<<<Btot / SPB, 256, 0, stream>>>(f1, f2, Wf1, Wf2, be1, be2, ivb);
    mica_tail<<<Btot / SPB, 256, 0, stream>>>(ivb, Waffa, Waffv, Wa, Wv,
                                              Wca, Wcv, Wha, Whv, G, c, outp);
}